// Round 7
// baseline (249.824 us; speedup 1.0000x reference)
//
#include <hip/hip_runtime.h>
#include <hip/hip_bf16.h>
#include <cfloat>
#include <cstdint>

#define Bb 4
#define Ss 512
#define Dd 768
#define Hh 12
#define HDd 64
#define NREL 101

typedef __attribute__((ext_vector_type(8))) short bfrag;
typedef __attribute__((ext_vector_type(4))) float f32x4;
typedef __attribute__((ext_vector_type(8))) unsigned short u16x8;

static __device__ __forceinline__ unsigned short f2bf(float x) {
  union { __hip_bfloat16 h; unsigned short u; } c;
  c.h = __float2bfloat16(x);
  return c.u;
}
static __device__ __forceinline__ float bf2f(unsigned short u) {
  return __uint_as_float(((unsigned int)u) << 16);
}
static __device__ __forceinline__ f32x4 mfma3(bfrag a, bfrag b, f32x4 c) {
  return __builtin_amdgcn_mfma_f32_16x16x32_bf16(a, b, c, 0, 0, 0);
}
static __device__ __forceinline__ void gload16(const void* g, void* l) {
  __builtin_amdgcn_global_load_lds((const __attribute__((address_space(1))) void*)g,
                                   (__attribute__((address_space(3))) void*)l, 16, 0, 0);
}

// ---------------- graph_arc dtype detector ----------------
__global__ void detect_kernel(const int* __restrict__ g, int* __restrict__ flag) {
  __shared__ int anynz;
  if (threadIdx.x == 0) anynz = 0;
  __syncthreads();
  int acc = 0;
  for (int i = threadIdx.x; i < 4096; i += 256) acc |= g[2 * i + 1];
  if (acc != 0) atomicOr(&anynz, 1);
  __syncthreads();
  if (threadIdx.x == 0) *flag = (anynz == 0) ? 1 : 0;  // 1 => int64
}

// ---------------- graph_arc -> u8 compaction ----------------
__global__ __launch_bounds__(256) void relcvt_kernel(const int* __restrict__ g,
                                                     const int* __restrict__ flag,
                                                     unsigned char* __restrict__ rel8) {
  const int idx = blockIdx.x * 256 + threadIdx.x;   // one per 4 elems; 262144 total
  uchar4 o;
  if (*flag) {
    const int4* p = (const int4*)g + (size_t)idx * 2;
    int4 a = p[0], b = p[1];
    o = make_uchar4((unsigned char)a.x, (unsigned char)a.z,
                    (unsigned char)b.x, (unsigned char)b.z);
  } else {
    int4 a = ((const int4*)g)[idx];
    o = make_uchar4((unsigned char)a.x, (unsigned char)a.y,
                    (unsigned char)a.z, (unsigned char)a.w);
  }
  ((uchar4*)rel8)[idx] = o;
}

// ---------------- E-matrices -> padded swizzled bf16 hi/lo (one pass) ----------------
// ek/eq: [112][64]; evt: [64][128] (= Ev^T zero-padded).
__global__ __launch_bounds__(256) void ecvt_kernel(
    const float* __restrict__ Ek, const float* __restrict__ Eq, const float* __restrict__ Ev,
    unsigned short* __restrict__ ekH, unsigned short* __restrict__ ekL,
    unsigned short* __restrict__ eqH, unsigned short* __restrict__ eqL,
    unsigned short* __restrict__ evtH, unsigned short* __restrict__ evtL)
{
  const int i = blockIdx.x * 256 + threadIdx.x;   // 1024 threads
  if (i < 896) {   // ek/eq: 112 rows x 8 slots
    const int row = i >> 3, s8 = i & 7;
    u16x8 H1, L1, H2, L2;
#pragma unroll
    for (int j = 0; j < 8; j++) {
      const float a = (row < NREL) ? Ek[row * 64 + s8 * 8 + j] : 0.f;
      const float b = (row < NREL) ? Eq[row * 64 + s8 * 8 + j] : 0.f;
      unsigned short h1 = f2bf(a); H1[j] = h1; L1[j] = f2bf(a - bf2f(h1));
      unsigned short h2 = f2bf(b); H2[j] = h2; L2[j] = f2bf(b - bf2f(h2));
    }
    const size_t dst = (size_t)row * 64 + (size_t)((s8 ^ (row & 7)) << 3);
    *(u16x8*)&ekH[dst] = H1; *(u16x8*)&ekL[dst] = L1;
    *(u16x8*)&eqH[dst] = H2; *(u16x8*)&eqL[dst] = L2;
  }
  if (i < 1024) {  // evt: 64 rows x 16 slots
    const int d = i >> 4, s8 = i & 15;
    const int c = s8 >> 3, sl = s8 & 7;
    u16x8 H, L;
#pragma unroll
    for (int j = 0; j < 8; j++) {
      const int g = c * 64 + sl * 8 + j;
      const float v = (g < NREL) ? Ev[g * 64 + d] : 0.f;
      unsigned short h = f2bf(v); H[j] = h; L[j] = f2bf(v - bf2f(h));
    }
    const size_t dst = (size_t)d * 128 + c * 64 + (size_t)((sl ^ (d & 7)) << 3);
    *(u16x8*)&evtH[dst] = H; *(u16x8*)&evtL[dst] = L;
  }
}

// ---------------- f32 -> swizzled bf16 hi/lo converter (inputs & weights) ----------------
struct CvtJob { const float* src; unsigned short* hi; unsigned short* lo; int rowlen; int nslots; };
struct Cvt8 { CvtJob j[8]; };

__global__ __launch_bounds__(256) void convert_kernel(Cvt8 jobs) {
  CvtJob jb = jobs.j[blockIdx.z];
  int idx = blockIdx.x * 256 + threadIdx.x;
  if (idx >= jb.nslots) return;
  const int spr = jb.rowlen >> 3;
  const int row = idx / spr;
  const int srem = idx - row * spr;
  const int c = srem >> 3, s8 = srem & 7;
  const float4* s4 = (const float4*)(jb.src + (size_t)idx * 8);
  float4 v0 = s4[0], v1 = s4[1];
  float e[8] = {v0.x, v0.y, v0.z, v0.w, v1.x, v1.y, v1.z, v1.w};
  u16x8 H, L;
#pragma unroll
  for (int i = 0; i < 8; i++) {
    unsigned short h = f2bf(e[i]);
    H[i] = h;
    L[i] = f2bf(e[i] - bf2f(h));
  }
  size_t dst = (size_t)row * jb.rowlen + c * 64 + (size_t)((s8 ^ (row & 7)) * 8);
  *(u16x8*)(jb.hi + dst) = H;
  *(u16x8*)(jb.lo + dst) = L;
}

// ---------------- GEMM: Y = X @ W^T + bias (split-bf16 MFMA) ----------------
// mode 0 (QKV): z=0 -> q hi/lo [bh][s][64] swz; z=1 -> k same; z=2 -> vt hi/lo [bh][d][512] swz.
// mode 1 (O): f32 row-major to Yf.
__global__ __launch_bounds__(256, 2) void gemm_mfma(
    const unsigned short* __restrict__ Xh0, const unsigned short* __restrict__ Xl0,
    const unsigned short* __restrict__ Xh1, const unsigned short* __restrict__ Xl1,
    const unsigned short* __restrict__ Xh2, const unsigned short* __restrict__ Xl2,
    const unsigned short* __restrict__ Wh0, const unsigned short* __restrict__ Wl0,
    const unsigned short* __restrict__ Wh1, const unsigned short* __restrict__ Wl1,
    const unsigned short* __restrict__ Wh2, const unsigned short* __restrict__ Wl2,
    const float* __restrict__ b0, const float* __restrict__ b1, const float* __restrict__ b2,
    float* __restrict__ Yf,
    unsigned short* __restrict__ oH0, unsigned short* __restrict__ oL0,
    unsigned short* __restrict__ oH1, unsigned short* __restrict__ oL1,
    unsigned short* __restrict__ oH2, unsigned short* __restrict__ oL2,
    int mode)
{
  __shared__ __align__(16) unsigned short Ah[128 * 64], Al[128 * 64];
  __shared__ __align__(16) unsigned short Bh[128 * 64], Bl[128 * 64];

  const int t = threadIdx.x;
  const int lane = t & 63, w = t >> 6;
  const int lg = lane >> 4, lc = lane & 15;
  const int wr = w >> 1, wc = w & 1;
  const int m0 = blockIdx.y * 128, n0 = blockIdx.x * 128;
  const int z = blockIdx.z;
  const unsigned short* Xh = (z == 0) ? Xh0 : (z == 1) ? Xh1 : Xh2;
  const unsigned short* Xl = (z == 0) ? Xl0 : (z == 1) ? Xl1 : Xl2;
  const unsigned short* Wh = (z == 0) ? Wh0 : (z == 1) ? Wh1 : Wh2;
  const unsigned short* Wl = (z == 0) ? Wl0 : (z == 1) ? Wl1 : Wl2;
  const float* bias = (z == 0) ? b0 : (z == 1) ? b1 : b2;

  f32x4 acc[4][4];
#pragma unroll
  for (int m = 0; m < 4; m++)
#pragma unroll
    for (int n = 0; n < 4; n++) acc[m][n] = (f32x4){0.f, 0.f, 0.f, 0.f};

  const int srow = t >> 3;
  const int scol = (t & 7) * 8;

  for (int c = 0; c < 12; c++) {
#pragma unroll
    for (int i = 0; i < 4; i++) {
      size_t ga = (size_t)(m0 + i * 32 + srow) * Dd + c * 64 + scol;
      size_t gb = (size_t)(n0 + i * 32 + srow) * Dd + c * 64 + scol;
      gload16(Xh + ga, &Ah[i * 2048 + t * 8]);
      gload16(Xl + ga, &Al[i * 2048 + t * 8]);
      gload16(Wh + gb, &Bh[i * 2048 + t * 8]);
      gload16(Wl + gb, &Bl[i * 2048 + t * 8]);
    }
    __syncthreads();
#pragma unroll
    for (int ks = 0; ks < 2; ks++) {
      bfrag ah[4], al[4];
#pragma unroll
      for (int m = 0; m < 4; m++) {
        const int aidx = (wr * 64 + m * 16 + lc) * 64 + (((ks * 4 + lg) ^ (lc & 7)) * 8);
        ah[m] = *(const bfrag*)&Ah[aidx];
        al[m] = *(const bfrag*)&Al[aidx];
      }
#pragma unroll
      for (int n = 0; n < 4; n++) {
        const int bidx = (wc * 64 + n * 16 + lc) * 64 + (((ks * 4 + lg) ^ (lc & 7)) * 8);
        bfrag bh = *(const bfrag*)&Bh[bidx];
        bfrag bl = *(const bfrag*)&Bl[bidx];
#pragma unroll
        for (int m = 0; m < 4; m++) {
          acc[m][n] = mfma3(ah[m], bh, acc[m][n]);
          acc[m][n] = mfma3(ah[m], bl, acc[m][n]);
          acc[m][n] = mfma3(al[m], bh, acc[m][n]);
        }
      }
    }
    __syncthreads();
  }

  if (mode == 1) {
#pragma unroll
    for (int n = 0; n < 4; n++) {
      const int col = n0 + wc * 64 + n * 16 + lc;
      const float badd = bias[col];
#pragma unroll
      for (int m = 0; m < 4; m++) {
        const int rbase = m0 + wr * 64 + m * 16 + 4 * lg;
#pragma unroll
        for (int i = 0; i < 4; i++)
          Yf[(size_t)(rbase + i) * Dd + col] = acc[m][n][i] + badd;
      }
    }
  } else {
    unsigned short* dH = (z == 0) ? oH0 : (z == 1) ? oH1 : oH2;
    unsigned short* dL = (z == 0) ? oL0 : (z == 1) ? oL1 : oL2;
#pragma unroll
    for (int n = 0; n < 4; n++) {
      const int col = n0 + wc * 64 + n * 16 + lc;
      const int h = col >> 6, d = col & 63;
      const float badd = bias[col];
#pragma unroll
      for (int m = 0; m < 4; m++) {
        const int rbase = m0 + wr * 64 + m * 16 + 4 * lg;
#pragma unroll
        for (int i = 0; i < 4; i++) {
          const int row = rbase + i;
          const int b = row >> 9, s = row & 511;
          const float val = acc[m][n][i] + badd;
          const unsigned short hh = f2bf(val);
          const unsigned short ll = f2bf(val - bf2f(hh));
          size_t pos;
          if (z < 2) {   // [bh*512+s][64] swizzled by s&7
            const size_t R = ((size_t)b * Hh + h) * Ss + s;
            pos = (R << 6) + (size_t)((((d >> 3) ^ (s & 7)) << 3) + (d & 7));
          } else {       // V^T: [bh*64+d][512] swizzled by d&7
            const size_t R = ((size_t)b * Hh + h) * (size_t)HDd + d;
            pos = R * Ss + (size_t)((s >> 6) << 6) +
                  (size_t)(((((s & 63) >> 3) ^ (d & 7)) << 3) + (s & 7));
          }
          dH[pos] = hh;
          dL[pos] = ll;
        }
      }
    }
  }
}

// ---------------- barrier-free streaming graph attention (prefetched) ----------------
__global__ __launch_bounds__(256, 3) void attn_kernel(
    const unsigned short* __restrict__ qHg, const unsigned short* __restrict__ qLg,
    const unsigned short* __restrict__ kHg, const unsigned short* __restrict__ kLg,
    const unsigned short* __restrict__ vtHg, const unsigned short* __restrict__ vtLg,
    const unsigned short* __restrict__ ekH, const unsigned short* __restrict__ ekL,
    const unsigned short* __restrict__ eqH, const unsigned short* __restrict__ eqL,
    const unsigned short* __restrict__ evtH, const unsigned short* __restrict__ evtL,
    const int* __restrict__ msk, const unsigned char* __restrict__ rel8,
    unsigned short* __restrict__ ctxH, unsigned short* __restrict__ ctxL)
{
  __shared__ __align__(16) unsigned short table[2][16 * 112];
  __shared__ __align__(16) float wsum[2][16 * 112];
  __shared__ __align__(16) unsigned short pbuf[2][2][16 * 32];
  __shared__ __align__(16) float osum[2][64 * 16];
  __shared__ __align__(16) unsigned short wsumBF[2][16 * 128];
  __shared__ __align__(16) float l_t[2][16];

  const int t = threadIdx.x;
  const int lane = t & 63, w = t >> 6;
  const int lg = lane >> 4, lc = lane & 15;
  const int tile = w >> 1, half = w & 1;
  const int h = blockIdx.y, b = blockIdx.z;
  const int q0 = (blockIdx.x * 2 + tile) * 16;
  const size_t bh = (size_t)b * Hh + h;

  for (int i = t; i < 2 * 16 * 112; i += 256) ((float*)wsum)[i] = 0.f;
  if (t < 32) ((float*)l_t)[t] = 0.f;

  // B-operand fragments: Q rows and K@q rows (hi/lo)
  bfrag qh[2], ql[2];
  {
    const size_t roff = (bh * Ss + q0 + lc) << 6;
    bfrag kqh[2], kql[2];
#pragma unroll
    for (int es = 0; es < 2; es++) {
      const int sw = ((es * 4 + lg) ^ (lc & 7)) * 8;
      qh[es] = *(const bfrag*)&qHg[roff + sw];
      ql[es] = *(const bfrag*)&qLg[roff + sw];
      kqh[es] = *(const bfrag*)&kHg[roff + sw];
      kql[es] = *(const bfrag*)&kLg[roff + sw];
    }
    const int rc0 = half ? 4 : 0, rc1 = half ? 7 : 4;
    for (int rc = rc0; rc < rc1; rc++) {
      f32x4 acc = {0.f, 0.f, 0.f, 0.f};
      const size_t eoff = (size_t)(rc * 16 + lc) << 6;
#pragma unroll
      for (int es = 0; es < 2; es++) {
        const int sw = ((es * 4 + lg) ^ (lc & 7)) * 8;
        bfrag a1 = *(const bfrag*)&ekH[eoff + sw];
        bfrag a2 = *(const bfrag*)&ekL[eoff + sw];
        bfrag a3 = *(const bfrag*)&eqH[eoff + sw];
        bfrag a4 = *(const bfrag*)&eqL[eoff + sw];
        acc = mfma3(a1, qh[es], acc);
        acc = mfma3(a1, ql[es], acc);
        acc = mfma3(a2, qh[es], acc);
        acc = mfma3(a3, kqh[es], acc);
        acc = mfma3(a3, kql[es], acc);
        acc = mfma3(a4, kqh[es], acc);
      }
#pragma unroll
      for (int i = 0; i < 4; i++)
        table[tile][lc * 112 + rc * 16 + 4 * lg + i] = f2bf(acc[i]);
    }
  }
  __syncthreads();  // barrier 1

  // streaming main loop: 8 windows of 32 kv, K prefetch depth 1 + V prefetch
  f32x4 oacc[4];
#pragma unroll
  for (int d = 0; d < 4; d++) oacc[d] = (f32x4){0.f, 0.f, 0.f, 0.f};
  float lsum = 0.f;
  const int* mrow = msk + b * Ss;
  const unsigned char* relrow = rel8 + ((size_t)b * Ss + q0 + lc) * Ss;
  unsigned short* pb = &pbuf[tile][half][0];
  const unsigned short* tab = &table[tile][lc * 112];
  float* ws_row = &wsum[tile][lc * 112];

  const int kvb = half * 256;
  const size_t kbase = (bh * Ss + kvb + lc) << 6;
  const int sw0 = (lg ^ (lc & 7)) * 8;
  const int sw1 = ((4 + lg) ^ (lc & 7)) * 8;

  bfrag c_kh[2][2], c_kl[2][2];
#pragma unroll
  for (int blk = 0; blk < 2; blk++) {
    const size_t ko = kbase + (size_t)(blk * 16) * 64;
    c_kh[blk][0] = *(const bfrag*)&kHg[ko + sw0];
    c_kh[blk][1] = *(const bfrag*)&kHg[ko + sw1];
    c_kl[blk][0] = *(const bfrag*)&kLg[ko + sw0];
    c_kl[blk][1] = *(const bfrag*)&kLg[ko + sw1];
  }

  for (int win = 0; win < 8; win++) {
    const int kv0 = kvb + win * 32;
    // V prefetch for this window
    bfrag vh[4], vl[4];
    {
      const int col = kv0 + 8 * lg;
      const int cchunk = col >> 6, slot = (col & 63) >> 3;
#pragma unroll
      for (int dblk = 0; dblk < 4; dblk++) {
        const int drow = dblk * 16 + lc;
        const size_t va = (bh * (size_t)HDd + drow) * Ss +
                          (size_t)(cchunk << 6) + (size_t)((slot ^ (drow & 7)) << 3);
        vh[dblk] = *(const bfrag*)&vtHg[va];
        vl[dblk] = *(const bfrag*)&vtLg[va];
      }
    }
    // K prefetch for next window
    bfrag n_kh[2][2], n_kl[2][2];
    if (win < 7) {
      const size_t kb2 = kbase + (size_t)((win + 1) * 32) * 64;
#pragma unroll
      for (int blk = 0; blk < 2; blk++) {
        const size_t ko = kb2 + (size_t)(blk * 16) * 64;
        n_kh[blk][0] = *(const bfrag*)&kHg[ko + sw0];
        n_kh[blk][1] = *(const bfrag*)&kHg[ko + sw1];
        n_kl[blk][0] = *(const bfrag*)&kLg[ko + sw0];
        n_kl[blk][1] = *(const bfrag*)&kLg[ko + sw1];
      }
    }
    // QK^T for both 16-blocks
    f32x4 acc0 = {0.f, 0.f, 0.f, 0.f}, acc1 = {0.f, 0.f, 0.f, 0.f};
#pragma unroll
    for (int es = 0; es < 2; es++) {
      acc0 = mfma3(c_kh[0][es], qh[es], acc0);
      acc0 = mfma3(c_kh[0][es], ql[es], acc0);
      acc0 = mfma3(c_kl[0][es], qh[es], acc0);
      acc1 = mfma3(c_kh[1][es], qh[es], acc1);
      acc1 = mfma3(c_kh[1][es], ql[es], acc1);
      acc1 = mfma3(c_kl[1][es], qh[es], acc1);
    }
    // softmax + bins + pack P
#pragma unroll
    for (int blk = 0; blk < 2; blk++) {
      const f32x4 a = blk ? acc1 : acc0;
      float wv[4];
#pragma unroll
      for (int i = 0; i < 4; i++) {
        const int kv = kv0 + blk * 16 + 4 * lg + i;
        const int g = relrow[kv];
        const float s = (a[i] + bf2f(tab[g])) * 0.125f;
        const float e = __expf(s);
        wv[i] = (mrow[kv] != 0) ? e : 0.f;
        lsum += wv[i];
        if (wv[i] > 0.f) atomicAdd(&ws_row[g], wv[i]);
      }
      unsigned int p01 = (unsigned int)f2bf(wv[0]) | ((unsigned int)f2bf(wv[1]) << 16);
      unsigned int p23 = (unsigned int)f2bf(wv[2]) | ((unsigned int)f2bf(wv[3]) << 16);
      *(uint2*)&pb[lc * 32 + blk * 16 + 4 * lg] = make_uint2(p01, p23);
    }
    // PV with prefetched V
    bfrag pa = *(const bfrag*)&pb[lc * 32 + 8 * lg];
#pragma unroll
    for (int dblk = 0; dblk < 4; dblk++) {
      oacc[dblk] = mfma3(pa, vh[dblk], oacc[dblk]);
      oacc[dblk] = mfma3(pa, vl[dblk], oacc[dblk]);
    }
    // rotate K registers
    if (win < 7) {
#pragma unroll
      for (int blk = 0; blk < 2; blk++)
#pragma unroll
        for (int es = 0; es < 2; es++) {
          c_kh[blk][es] = n_kh[blk][es];
          c_kl[blk][es] = n_kl[blk][es];
        }
    }
  }

  lsum += __shfl_xor(lsum, 16);
  lsum += __shfl_xor(lsum, 32);
  if (lg == 0) atomicAdd(&l_t[tile][lc], lsum);

  if (half == 0) {
#pragma unroll
    for (int dblk = 0; dblk < 4; dblk++)
      *(f32x4*)&osum[tile][lane * 16 + dblk * 4] = oacc[dblk];
  }
  __syncthreads();  // barrier 2
  if (half == 0) return;

#pragma unroll
  for (int dblk = 0; dblk < 4; dblk++)
    oacc[dblk] += *(const f32x4*)&osum[tile][lane * 16 + dblk * 4];

  {
    const int qq = lane >> 2, seg = lane & 3;
#pragma unroll
    for (int jp = 0; jp < 16; jp++) {
      const int col = seg * 32 + jp * 2;
      const float v0 = (col < 112) ? wsum[tile][qq * 112 + col] : 0.f;
      const float v1 = (col + 1 < 112) ? wsum[tile][qq * 112 + col + 1] : 0.f;
      *(unsigned int*)&wsumBF[tile][qq * 128 + col] =
          (unsigned int)f2bf(v0) | ((unsigned int)f2bf(v1) << 16);
    }
  }

  f32x4 evacc[4];
#pragma unroll
  for (int d = 0; d < 4; d++) evacc[d] = (f32x4){0.f, 0.f, 0.f, 0.f};
#pragma unroll
  for (int es = 0; es < 4; es++) {
    bfrag pw = *(const bfrag*)&wsumBF[tile][lc * 128 + es * 32 + 8 * lg];
    const int col = es * 32 + 8 * lg;
    const int cchunk = col >> 6, slot = (col & 63) >> 3;
#pragma unroll
    for (int dblk = 0; dblk < 4; dblk++) {
      const int drow = dblk * 16 + lc;
      const size_t ea = (size_t)drow * 128 + (size_t)(cchunk << 6) +
                        (size_t)((slot ^ (drow & 7)) << 3);
      bfrag eh = *(const bfrag*)&evtH[ea];
      bfrag el = *(const bfrag*)&evtL[ea];
      evacc[dblk] = mfma3(pw, eh, evacc[dblk]);
      evacc[dblk] = mfma3(pw, el, evacc[dblk]);
    }
  }

  float rv[4];
#pragma unroll
  for (int i = 0; i < 4; i++) {
    const float lv = l_t[tile][4 * lg + i];
    rv[i] = (lv > 0.f) ? 1.f / lv : 0.f;
  }
#pragma unroll
  for (int dblk = 0; dblk < 4; dblk++) {
    const int d = dblk * 16 + lc;
    const int slot = d >> 3, pos = d & 7;
#pragma unroll
    for (int i = 0; i < 4; i++) {
      const int qrow = q0 + 4 * lg + i;
      const int r7 = qrow & 7;
      const float val = (oacc[dblk][i] + evacc[dblk][i]) * rv[i];
      const unsigned short hh = f2bf(val);
      const unsigned short ll = f2bf(val - bf2f(hh));
      const size_t base = ((size_t)b * Ss + qrow) * Dd + h * 64 +
                          (size_t)((slot ^ r7) << 3) + pos;
      ctxH[base] = hh;
      ctxL[base] = ll;
    }
  }
}

extern "C" void kernel_launch(void* const* d_in, const int* in_sizes, int n_in,
                              void* d_out, int out_size, void* d_ws, size_t ws_size,
                              hipStream_t stream) {
  const float* query = (const float*)d_in[0];
  const float* key   = (const float*)d_in[1];
  const float* value = (const float*)d_in[2];
  const int*   mask  = (const int*)d_in[3];
  const int*   garc  = (const int*)d_in[4];
  const float* Wq = (const float*)d_in[5];
  const float* bq = (const float*)d_in[6];
  const float* Wk = (const float*)d_in[7];
  const float* bk = (const float*)d_in[8];
  const float* Wv = (const float*)d_in[9];
  const float* bv = (const float*)d_in[10];
  const float* Wo = (const float*)d_in[11];
  const float* bo = (const float*)d_in[12];
  const float* Ek = (const float*)d_in[13];
  const float* Eq = (const float*)d_in[14];
  const float* Ev = (const float*)d_in[15];

  const size_t XE = (size_t)Bb * Ss * Dd;     // 1,572,864 activation elems
  const size_t WE = (size_t)Dd * Dd;          //   589,824 weight elems

  char* ws = (char*)d_ws;
  int* flag = (int*)ws;
  unsigned short* wq_h = (unsigned short*)(ws + 256);
  unsigned short* wq_l = wq_h + WE;
  unsigned short* wk_h = wq_l + WE;
  unsigned short* wk_l = wk_h + WE;
  unsigned short* wv_h = wk_l + WE;
  unsigned short* wv_l = wv_h + WE;
  unsigned short* wo_h = wv_l + WE;
  unsigned short* wo_l = wo_h + WE;
  unsigned short* xq_h = wo_l + WE;      unsigned short* xq_l = xq_h + XE;
  unsigned short* xk_h = xq_l + XE;      unsigned short* xk_l = xk_h + XE;
  unsigned short* xv_h = xk_l + XE;      unsigned short* xv_l = xv_h + XE;
  unsigned short* q_h  = xv_l + XE;      unsigned short* q_l  = q_h + XE;
  unsigned short* k_h  = q_l + XE;       unsigned short* k_l  = k_h + XE;
  unsigned short* vt_h = k_l + XE;       unsigned short* vt_l = vt_h + XE;
  unsigned short* ctx_h = vt_l + XE;     unsigned short* ctx_l = ctx_h + XE;
  unsigned char* rel8 = (unsigned char*)(ctx_l + XE);  // 1 MB
  unsigned short* ek_h  = (unsigned short*)(rel8 + (size_t)Bb * Ss * Ss);
  unsigned short* ek_l  = ek_h + 112 * 64;
  unsigned short* eq_h  = ek_l + 112 * 64;
  unsigned short* eq_l  = eq_h + 112 * 64;
  unsigned short* evt_h = eq_l + 112 * 64;
  unsigned short* evt_l = evt_h + 64 * 128;

  detect_kernel<<<1, 256, 0, stream>>>(garc, flag);
  relcvt_kernel<<<dim3(1024), 256, 0, stream>>>(garc, flag, rel8);
  ecvt_kernel<<<dim3(4), 256, 0, stream>>>(Ek, Eq, Ev, ek_h, ek_l, eq_h, eq_l, evt_h, evt_l);

  Cvt8 pre = {};
  pre.j[0] = {query, xq_h, xq_l, Dd, (int)(XE / 8)};
  pre.j[1] = {key,   xk_h, xk_l, Dd, (int)(XE / 8)};
  pre.j[2] = {value, xv_h, xv_l, Dd, (int)(XE / 8)};
  pre.j[3] = {Wq, wq_h, wq_l, Dd, (int)(WE / 8)};
  pre.j[4] = {Wk, wk_h, wk_l, Dd, (int)(WE / 8)};
  pre.j[5] = {Wv, wv_h, wv_l, Dd, (int)(WE / 8)};
  pre.j[6] = {Wo, wo_h, wo_l, Dd, (int)(WE / 8)};
  convert_kernel<<<dim3(768, 1, 7), 256, 0, stream>>>(pre);

  // QKV projections -> hi/lo swizzled bf16 directly (V transposed)
  gemm_mfma<<<dim3(6, 16, 3), 256, 0, stream>>>(
      xq_h, xq_l, xk_h, xk_l, xv_h, xv_l,
      wq_h, wq_l, wk_h, wk_l, wv_h, wv_l,
      bq, bk, bv, nullptr,
      q_h, q_l, k_h, k_l, vt_h, vt_l, 0);

  attn_kernel<<<dim3(16, 12, 4), 256, 0, stream>>>(
      q_h, q_l, k_h, k_l, vt_h, vt_l,
      ek_h, ek_l, eq_h, eq_l, evt_h, evt_l,
      mask, rel8, ctx_h, ctx_l);

  gemm_mfma<<<dim3(6, 16, 1), 256, 0, stream>>>(
      ctx_h, ctx_l, ctx_h, ctx_l, ctx_h, ctx_l,
      wo_h, wo_l, wo_h, wo_l, wo_h, wo_l,
      bo, bo, bo, (float*)d_out,
      nullptr, nullptr, nullptr, nullptr, nullptr, nullptr, 1);
}